// Round 10
// baseline (1102.980 us; speedup 1.0000x reference)
//
#include <hip/hip_runtime.h>
#include <stdint.h>
#include <stddef.h>

#define B_   16
#define T_   256
#define L_   1024
#define H_   1024
#define G3_  3072
#define KIN_ 96
#define CONVB_ 4096

// NaN bf16 pattern: can never be produced by the GRU (|h| <= 1, finite arithmetic)
#define SENT_     0x7FC1
#define SENT_X2_  0x7FC17FC1u

typedef __attribute__((ext_vector_type(8))) __bf16 bf16x8;
typedef __attribute__((ext_vector_type(4))) float  f32x4;
typedef __attribute__((ext_vector_type(4))) int    i32x4;

static __device__ __forceinline__ unsigned short f2bf(float x) {
  unsigned int u = __builtin_bit_cast(unsigned int, x);
  u += 0x7FFFu + ((u >> 16) & 1u);           // RNE
  return (unsigned short)(u >> 16);
}
static __device__ __forceinline__ float bf2f(unsigned short s) {
  unsigned int u = ((unsigned int)s) << 16;
  return __builtin_bit_cast(float, u);
}
// nonzero iff either 16-bit half of d equals the sentinel (exact SWAR detector)
static __device__ __forceinline__ unsigned sentmask(unsigned d) {
  const unsigned x = d ^ SENT_X2_;
  return (x - 0x00010001u) & ~x & 0x80008000u;
}

// ---------------------------------------------------------------- prep+conv
// One dispatch: blocks [0,4096) run conv+pool; remaining blocks grid-stride the
// prep work (bf16 converts, lateral transpose, hs sentinel fill, h0 zero,
// attention-ones). Plain stores; end-of-kernel L2 writeback publishes.
__global__ __launch_bounds__(256) void prep_conv_kernel(
    const float* __restrict__ x,
    const float* __restrict__ w3, const float* __restrict__ b3,
    const float* __restrict__ w5, const float* __restrict__ b5,
    const float* __restrict__ w7, const float* __restrict__ b7,
    unsigned short* __restrict__ feat,
    const float* __restrict__ whh,  unsigned short* __restrict__ whh_bf,
    const float* __restrict__ wih,  unsigned short* __restrict__ wih_bf,
    const float* __restrict__ fiw1, unsigned short* __restrict__ fiw1_bf,
    const float* __restrict__ fiw2, unsigned short* __restrict__ fiw2_bf,
    const float* __restrict__ lat,  unsigned short* __restrict__ latT_bf,
    unsigned short* __restrict__ hsbuf, float* __restrict__ attn_out) {
  __shared__ float xpad[L_ + 8];
  __shared__ float wlds[96][8];
  __shared__ float blds[96];
  __shared__ float wmax[4][96];
  const int tid = threadIdx.x;

  if (blockIdx.x >= CONVB_) {
    const int N0 = G3_ * H_;
    const int N1 = N0 + G3_ * KIN_;
    const int N2 = N1 + H_ * H_;
    const int N3 = N2 + H_ * H_;
    const int N4 = N3 + H_ * H_;             // lat transpose
    const int N5 = N4 + T_ * B_ * H_ / 2;    // hs sentinel (dword units)
    const int N6 = N5 + B_ * H_ / 2;         // hs h0 zero
    const int N7 = N6 + B_ * T_;             // attention ones
    int i = (blockIdx.x - CONVB_) * 256 + tid;
    const int stride = (gridDim.x - CONVB_) * 256;
    unsigned int* hs32 = (unsigned int*)hsbuf;
    for (; i < N7; i += stride) {
      if (i < N0)      whh_bf[i] = f2bf(whh[i]);
      else if (i < N1) { const int j = i - N0; wih_bf[j]  = f2bf(wih[j]); }
      else if (i < N2) { const int j = i - N1; fiw1_bf[j] = f2bf(fiw1[j]); }
      else if (i < N3) { const int j = i - N2; fiw2_bf[j] = f2bf(fiw2[j]); }
      else if (i < N4) { const int j = i - N3; const int r = j >> 10, c = j & 1023;
                         latT_bf[(size_t)c * H_ + r] = f2bf(lat[j]); }
      else if (i < N5) { hs32[B_ * H_ / 2 + (i - N4)] = SENT_X2_; }
      else if (i < N6) { hs32[i - N5] = 0u; }
      else             { attn_out[i - N6] = 1.0f; }
    }
    return;
  }

  const int rid = blockIdx.x;          // b*T + t
  const int b = rid >> 8;
  const int t = rid & 255;
  const float* xr = x + (size_t)rid * L_;
  for (int off = tid; off < L_; off += 256) xpad[off + 3] = xr[off];
  if (tid < 3) xpad[tid] = 0.f;
  if (tid >= 3 && tid < 8) xpad[L_ + tid] = 0.f;
  if (tid < 96) {
    const int f = tid;
    float wv[8];
#pragma unroll
    for (int k = 0; k < 8; ++k) wv[k] = 0.f;
    float bv;
    if (f < 32)      { for (int k = 0; k < 3; ++k) wv[k + 2] = w3[f * 3 + k]; bv = b3[f]; }
    else if (f < 64) { int ff = f - 32; for (int k = 0; k < 5; ++k) wv[k + 1] = w5[ff * 5 + k]; bv = b5[ff]; }
    else             { int ff = f - 64; for (int k = 0; k < 7; ++k) wv[k] = w7[ff * 7 + k]; bv = b7[ff]; }
#pragma unroll
    for (int k = 0; k < 8; ++k) wlds[f][k] = wv[k];
    blds[f] = bv;
  }
  __syncthreads();
  const int w = tid >> 6, lane = tid & 63;
  const int p0 = w * 256 + lane * 4;
  float xv[10];
#pragma unroll
  for (int i = 0; i < 10; ++i) xv[i] = xpad[p0 + i];
  for (int f = 0; f < 96; ++f) {
    float a0 = 0.f, a1 = 0.f, a2 = 0.f, a3 = 0.f;
#pragma unroll
    for (int k = 0; k < 7; ++k) {
      const float wk = wlds[f][k];
      a0 = fmaf(wk, xv[k],     a0);
      a1 = fmaf(wk, xv[k + 1], a1);
      a2 = fmaf(wk, xv[k + 2], a2);
      a3 = fmaf(wk, xv[k + 3], a3);
    }
    float m = fmaxf(fmaxf(a0, a1), fmaxf(a2, a3));
#pragma unroll
    for (int d = 1; d < 64; d <<= 1) m = fmaxf(m, __shfl_xor(m, d, 64));
    if (lane == 0) wmax[w][f] = m;
  }
  __syncthreads();
  if (tid < 96) {
    float m = fmaxf(fmaxf(wmax[0][tid], wmax[1][tid]),
                    fmaxf(wmax[2][tid], wmax[3][tid]));
    m += blds[tid];
    m = m > 0.f ? m : 0.f;
    feat[(size_t)(t * B_ + b) * KIN_ + tid] = f2bf(m);   // row = t*B + b
  }
}

// ---------------------------------------------------------------- GEMM
// C[M,N] = A[M,K] * B[N,K]^T  (both bf16, row-major). 128x128 tile, BK=32,
// 4 waves, double-buffered LDS, padded stride 40.
// EP: 1 = inhib = bf2f(A) - relu(acc) -> bf16; 2 = relu(acc+bias) -> bf16;
//     3 = acc+bias -> d_out[(b*T+t)*H + col].
template <int EP>
__global__ __launch_bounds__(256) void gemm_kernel(
    const unsigned short* __restrict__ A,
    const unsigned short* __restrict__ Bm,
    int M, int N, int K, int lda, int ldb,
    const float* __restrict__ bias,
    float* __restrict__ outF,
    unsigned short* __restrict__ outB) {
  __shared__ __align__(16) unsigned short As[2][128 * 40];
  __shared__ __align__(16) unsigned short Bs[2][128 * 40];
  const int tid = threadIdx.x;
  const int n0 = blockIdx.x * 128;
  const int m0 = blockIdx.y * 128;
  const int w = tid >> 6;
  const int l = tid & 63;
  const int lr = l & 15;
  const int lk = (l >> 4) * 8;
  const int srow = tid >> 2;
  const int skc = (tid & 3) * 8;

  f32x4 acc[2][8];
#pragma unroll
  for (int i = 0; i < 2; ++i)
#pragma unroll
    for (int j = 0; j < 8; ++j) acc[i][j] = (f32x4){0.f, 0.f, 0.f, 0.f};

  const int NK = K >> 5;
  const unsigned short* Aptr  = A  + (size_t)(m0 + srow)      * lda + skc;
  const unsigned short* Aptr2 = A  + (size_t)(m0 + 64 + srow) * lda + skc;
  const unsigned short* Bptr  = Bm + (size_t)(n0 + srow)      * ldb + skc;
  const unsigned short* Bptr2 = Bm + (size_t)(n0 + 64 + srow) * ldb + skc;

  i32x4 ar0 = *(const i32x4*)(Aptr);
  i32x4 ar1 = *(const i32x4*)(Aptr2);
  i32x4 br0 = *(const i32x4*)(Bptr);
  i32x4 br1 = *(const i32x4*)(Bptr2);
  *(i32x4*)&As[0][srow * 40 + skc]        = ar0;
  *(i32x4*)&As[0][(64 + srow) * 40 + skc] = ar1;
  *(i32x4*)&Bs[0][srow * 40 + skc]        = br0;
  *(i32x4*)&Bs[0][(64 + srow) * 40 + skc] = br1;
  __syncthreads();

  for (int kk = 0; kk < NK; ++kk) {
    const int cur = kk & 1;
    if (kk + 1 < NK) {
      const int ko = (kk + 1) << 5;
      ar0 = *(const i32x4*)(Aptr  + ko);
      ar1 = *(const i32x4*)(Aptr2 + ko);
      br0 = *(const i32x4*)(Bptr  + ko);
      br1 = *(const i32x4*)(Bptr2 + ko);
    }
    const bf16x8 a0 = *(const bf16x8*)&As[cur][(w * 32 + lr) * 40 + lk];
    const bf16x8 a1 = *(const bf16x8*)&As[cur][(w * 32 + 16 + lr) * 40 + lk];
#pragma unroll
    for (int nt = 0; nt < 8; ++nt) {
      const bf16x8 bb = *(const bf16x8*)&Bs[cur][(nt * 16 + lr) * 40 + lk];
      acc[0][nt] = __builtin_amdgcn_mfma_f32_16x16x32_bf16(a0, bb, acc[0][nt], 0, 0, 0);
      acc[1][nt] = __builtin_amdgcn_mfma_f32_16x16x32_bf16(a1, bb, acc[1][nt], 0, 0, 0);
    }
    __syncthreads();
    if (kk + 1 < NK) {
      const int nxt = cur ^ 1;
      *(i32x4*)&As[nxt][srow * 40 + skc]        = ar0;
      *(i32x4*)&As[nxt][(64 + srow) * 40 + skc] = ar1;
      *(i32x4*)&Bs[nxt][srow * 40 + skc]        = br0;
      *(i32x4*)&Bs[nxt][(64 + srow) * 40 + skc] = br1;
    }
    __syncthreads();
  }

#pragma unroll
  for (int mt = 0; mt < 2; ++mt) {
#pragma unroll
    for (int nt = 0; nt < 8; ++nt) {
      const f32x4 v = acc[mt][nt];
      const int gcol = n0 + nt * 16 + lr;
#pragma unroll
      for (int e = 0; e < 4; ++e) {
        const int grow = m0 + w * 32 + mt * 16 + (l >> 4) * 4 + e;
        const float val = v[e];
        if (EP == 1) {
          const float hsv = bf2f(A[(size_t)grow * lda + gcol]);
          outB[(size_t)grow * N + gcol] = f2bf(hsv - fmaxf(val, 0.f));
        } else if (EP == 2) {
          outB[(size_t)grow * N + gcol] = f2bf(fmaxf(val + bias[gcol], 0.f));
        } else {
          const int tt = grow >> 4;   // row = t*B + b
          const int bb2 = grow & 15;
          outF[((size_t)bb2 * T_ + tt) * H_ + gcol] = val + bias[gcol];
        }
      }
    }
  }
}

// ---------------------------------------------------------------- GRU scan
// Proven round-4/9 dataflow protocol (64 WGs, 512 thr, 16 cols/WG, pinned
// weight quads, single barrier/step, sentinel data-signal, sc0 sc1,
// shuffle-packed 16B publish) + two slack-filling additions:
//  (1) inline x-gates: waves 0-2 compute step t+1's gate tile (feat x W_ih
//      slice, K=96 -> 3 MFMAs each) in the tail of step t into a
//      double-buffered LDS tile — removes the separate gates GEMM + 50MB.
//  (2) speculative next-step poll: t+1's sentinel loads issue at end of step
//      t; loop top checks them and skips the poll loop on full-wave hit.
__global__ __launch_bounds__(512, 2) void gru_scan_kernel(
    const unsigned short* __restrict__ Whh,   // [3072][1024] bf16
    const unsigned short* __restrict__ Wih,   // [3072][96] bf16
    const unsigned short* __restrict__ feat,  // [T*B][96] bf16
    const float* __restrict__ bhh,            // [3072]
    const float* __restrict__ bih,            // [3072]
    unsigned short* __restrict__ hs) {        // [T+1][B][H]; slice0 = 0
  const int g = blockIdx.x;                   // worker id 0..63
  const int tid = threadIdx.x;

  __shared__ float ghp[2][8][3][16][17];      // [buf][wave][gate][batch][j]
  __shared__ float gxS[2][3][16][17];         // [buf][gate][batch][j]
  const int w = tid >> 6;                     // wave: K-slice [128w, 128w+128)
  const int l = tid & 63;
  const int lr = l & 15;
  const int lk8 = (l >> 4) * 8;
  const int j0 = g * 16;
  const int wg = (w < 3) ? w : 0;             // gate id for mini-MFMA waves

  // ---- one-time: 12 W_hh quads + 3 W_ih quads into named registers
  const unsigned short* ap0 = Whh + (size_t)(j0 + lr) * H_ + w * 128 + lk8;
  const unsigned short* ap1 = ap0 + (size_t)H_ * H_;
  const unsigned short* ap2 = ap1 + (size_t)H_ * H_;
  const unsigned short* agp = Wih + (size_t)(wg * H_ + j0 + lr) * KIN_ + lk8;
  i32x4 w00, w01, w02, w03, w10, w11, w12, w13, w20, w21, w22, w23, q0, q1, q2;
  asm volatile(
      "global_load_dwordx4 %0,  %15, off\n\t"
      "global_load_dwordx4 %1,  %15, off offset:64\n\t"
      "global_load_dwordx4 %2,  %15, off offset:128\n\t"
      "global_load_dwordx4 %3,  %15, off offset:192\n\t"
      "global_load_dwordx4 %4,  %16, off\n\t"
      "global_load_dwordx4 %5,  %16, off offset:64\n\t"
      "global_load_dwordx4 %6,  %16, off offset:128\n\t"
      "global_load_dwordx4 %7,  %16, off offset:192\n\t"
      "global_load_dwordx4 %8,  %17, off\n\t"
      "global_load_dwordx4 %9,  %17, off offset:64\n\t"
      "global_load_dwordx4 %10, %17, off offset:128\n\t"
      "global_load_dwordx4 %11, %17, off offset:192\n\t"
      "global_load_dwordx4 %12, %18, off\n\t"
      "global_load_dwordx4 %13, %18, off offset:64\n\t"
      "global_load_dwordx4 %14, %18, off offset:128\n\t"
      "s_waitcnt vmcnt(0)"
      : "=&v"(w00), "=&v"(w01), "=&v"(w02), "=&v"(w03),
        "=&v"(w10), "=&v"(w11), "=&v"(w12), "=&v"(w13),
        "=&v"(w20), "=&v"(w21), "=&v"(w22), "=&v"(w23),
        "=&v"(q0), "=&v"(q1), "=&v"(q2)
      : "v"(ap0), "v"(ap1), "v"(ap2), "v"(agp));
  const bf16x8 af00 = __builtin_bit_cast(bf16x8, w00);
  const bf16x8 af01 = __builtin_bit_cast(bf16x8, w01);
  const bf16x8 af02 = __builtin_bit_cast(bf16x8, w02);
  const bf16x8 af03 = __builtin_bit_cast(bf16x8, w03);
  const bf16x8 af10 = __builtin_bit_cast(bf16x8, w10);
  const bf16x8 af11 = __builtin_bit_cast(bf16x8, w11);
  const bf16x8 af12 = __builtin_bit_cast(bf16x8, w12);
  const bf16x8 af13 = __builtin_bit_cast(bf16x8, w13);
  const bf16x8 af20 = __builtin_bit_cast(bf16x8, w20);
  const bf16x8 af21 = __builtin_bit_cast(bf16x8, w21);
  const bf16x8 af22 = __builtin_bit_cast(bf16x8, w22);
  const bf16x8 af23 = __builtin_bit_cast(bf16x8, w23);
  const bf16x8 ga0  = __builtin_bit_cast(bf16x8, q0);
  const bf16x8 ga1  = __builtin_bit_cast(bf16x8, q1);
  const bf16x8 ga2  = __builtin_bit_cast(bf16x8, q2);

  const int jb = tid & 15;   // j within chunk   (valid for tid < 256)
  const int bb = tid >> 4;   // batch
  const float bxr = bih[j0 + jb];             // x-gate biases
  const float bxz = bih[H_ + j0 + jb];
  const float bxn = bih[2 * H_ + j0 + jb];
  const float bhr = bhh[j0 + jb];             // h-gate biases
  const float bhz = bhh[H_ + j0 + jb];
  const float bhn = bhh[2 * H_ + j0 + jb];
  float hprev = 0.f;
  const int rb = (l >> 4) * 4;

  // gates for t=0 (waves 0-2)
  if (w < 3) {
    const unsigned short* fp = feat + (size_t)lr * KIN_ + lk8;  // row = 0*B+lr
    const bf16x8 fb0 = *(const bf16x8*)(fp);
    const bf16x8 fb1 = *(const bf16x8*)(fp + 32);
    const bf16x8 fb2 = *(const bf16x8*)(fp + 64);
    f32x4 G = (f32x4){0.f, 0.f, 0.f, 0.f};
    G = __builtin_amdgcn_mfma_f32_16x16x32_bf16(ga0, fb0, G, 0, 0, 0);
    G = __builtin_amdgcn_mfma_f32_16x16x32_bf16(ga1, fb1, G, 0, 0, 0);
    G = __builtin_amdgcn_mfma_f32_16x16x32_bf16(ga2, fb2, G, 0, 0, 0);
#pragma unroll
    for (int e = 0; e < 4; ++e) gxS[0][w][lr][rb + e] = G[e];
  }
  __syncthreads();

  i32x4 u0, u1, u2, u3;
  int sv = 0;

  for (int t = 0; t < T_; ++t) {
    const int buf = t & 1;
    const unsigned short* hp = hs + (size_t)t * (B_ * H_) +
                               (size_t)lr * H_ + w * 128 + lk8;
    int got = 0;
    if (sv) {
      asm volatile("s_waitcnt vmcnt(0)" ::: "memory");
      __builtin_amdgcn_sched_barrier(0);
      const unsigned bad = sentmask(u0[0]) | sentmask(u0[3]) |
                           sentmask(u1[0]) | sentmask(u1[3]) |
                           sentmask(u2[0]) | sentmask(u2[3]) |
                           sentmask(u3[0]) | sentmask(u3[3]);
      got = (__ballot(bad == 0) == ~0ull) ? 1 : 0;
    }
    if (!got) {
      while (true) {
        asm volatile(
            "global_load_dwordx4 %0, %4, off sc0 sc1\n\t"
            "global_load_dwordx4 %1, %4, off offset:64 sc0 sc1\n\t"
            "global_load_dwordx4 %2, %4, off offset:128 sc0 sc1\n\t"
            "global_load_dwordx4 %3, %4, off offset:192 sc0 sc1\n\t"
            "s_waitcnt vmcnt(0)"
            : "=&v"(u0), "=&v"(u1), "=&v"(u2), "=&v"(u3)
            : "v"(hp)
            : "memory");
        const unsigned bad = sentmask(u0[0]) | sentmask(u0[3]) |
                             sentmask(u1[0]) | sentmask(u1[3]) |
                             sentmask(u2[0]) | sentmask(u2[3]) |
                             sentmask(u3[0]) | sentmask(u3[3]);
        if (__ballot(bad == 0) == ~0ull) break;
      }
    }
    const bf16x8 hf0 = __builtin_bit_cast(bf16x8, u0);
    const bf16x8 hf1 = __builtin_bit_cast(bf16x8, u1);
    const bf16x8 hf2 = __builtin_bit_cast(bf16x8, u2);
    const bf16x8 hf3 = __builtin_bit_cast(bf16x8, u3);

    f32x4 C0 = (f32x4){0.f, 0.f, 0.f, 0.f}, C1 = C0, C2 = C0;
    C0 = __builtin_amdgcn_mfma_f32_16x16x32_bf16(af00, hf0, C0, 0, 0, 0);
    C1 = __builtin_amdgcn_mfma_f32_16x16x32_bf16(af10, hf0, C1, 0, 0, 0);
    C2 = __builtin_amdgcn_mfma_f32_16x16x32_bf16(af20, hf0, C2, 0, 0, 0);
    C0 = __builtin_amdgcn_mfma_f32_16x16x32_bf16(af01, hf1, C0, 0, 0, 0);
    C1 = __builtin_amdgcn_mfma_f32_16x16x32_bf16(af11, hf1, C1, 0, 0, 0);
    C2 = __builtin_amdgcn_mfma_f32_16x16x32_bf16(af21, hf1, C2, 0, 0, 0);
    C0 = __builtin_amdgcn_mfma_f32_16x16x32_bf16(af02, hf2, C0, 0, 0, 0);
    C1 = __builtin_amdgcn_mfma_f32_16x16x32_bf16(af12, hf2, C1, 0, 0, 0);
    C2 = __builtin_amdgcn_mfma_f32_16x16x32_bf16(af22, hf2, C2, 0, 0, 0);
    C0 = __builtin_amdgcn_mfma_f32_16x16x32_bf16(af03, hf3, C0, 0, 0, 0);
    C1 = __builtin_amdgcn_mfma_f32_16x16x32_bf16(af13, hf3, C1, 0, 0, 0);
    C2 = __builtin_amdgcn_mfma_f32_16x16x32_bf16(af23, hf3, C2, 0, 0, 0);

#pragma unroll
    for (int e = 0; e < 4; ++e) {
      ghp[buf][w][0][lr][rb + e] = C0[e];
      ghp[buf][w][1][lr][rb + e] = C1[e];
      ghp[buf][w][2][lr][rb + e] = C2[e];
    }
    __syncthreads();   // single barrier per step; buffer parity protects reuse

    if (tid < 256) {
      const float gxr = gxS[buf][0][bb][jb] + bxr;
      const float gxz = gxS[buf][1][bb][jb] + bxz;
      const float gxn = gxS[buf][2][bb][jb] + bxn;
      float hr = bhr, hz = bhz, hn = bhn;
#pragma unroll
      for (int w2 = 0; w2 < 8; ++w2) {
        hr += ghp[buf][w2][0][bb][jb];
        hz += ghp[buf][w2][1][bb][jb];
        hn += ghp[buf][w2][2][bb][jb];
      }
      const float r = 1.f / (1.f + __expf(-(gxr + hr)));
      const float z = 1.f / (1.f + __expf(-(gxz + hz)));
      const float xn = gxn + r * hn;
      const float n = 2.f / (1.f + __expf(-2.f * xn)) - 1.f;
      const float hnew = (1.f - z) * n + z * hprev;   // carry stays fp32
      hprev = hnew;

      const unsigned hv = (unsigned)f2bf(hnew);
      const int base = l & ~7;
      const unsigned s0 = __shfl(hv, base + 0, 64);
      const unsigned s1 = __shfl(hv, base + 1, 64);
      const unsigned s2 = __shfl(hv, base + 2, 64);
      const unsigned s3 = __shfl(hv, base + 3, 64);
      const unsigned s4 = __shfl(hv, base + 4, 64);
      const unsigned s5 = __shfl(hv, base + 5, 64);
      const unsigned s6 = __shfl(hv, base + 6, 64);
      const unsigned s7 = __shfl(hv, base + 7, 64);
      i32x4 pk;
      pk[0] = (int)(s0 | (s1 << 16));
      pk[1] = (int)(s2 | (s3 << 16));
      pk[2] = (int)(s4 | (s5 << 16));
      pk[3] = (int)(s6 | (s7 << 16));
      if ((l & 7) == 0) {
        unsigned short* sp = hs + ((size_t)(t + 1) * B_ + bb) * H_ + j0 + (l & 15);
        asm volatile("global_store_dwordx4 %0, %1, off sc0 sc1"
                     :: "v"(sp), "v"(pk) : "memory");
      }
    }

    // tail: gates for t+1 (waves 0-2), then speculative polls for t+1
    if (t + 1 < T_) {
      if (w < 3) {
        const unsigned short* fp = feat + (size_t)((t + 1) * B_ + lr) * KIN_ + lk8;
        const bf16x8 fb0 = *(const bf16x8*)(fp);
        const bf16x8 fb1 = *(const bf16x8*)(fp + 32);
        const bf16x8 fb2 = *(const bf16x8*)(fp + 64);
        f32x4 G = (f32x4){0.f, 0.f, 0.f, 0.f};
        G = __builtin_amdgcn_mfma_f32_16x16x32_bf16(ga0, fb0, G, 0, 0, 0);
        G = __builtin_amdgcn_mfma_f32_16x16x32_bf16(ga1, fb1, G, 0, 0, 0);
        G = __builtin_amdgcn_mfma_f32_16x16x32_bf16(ga2, fb2, G, 0, 0, 0);
#pragma unroll
        for (int e = 0; e < 4; ++e) gxS[buf ^ 1][w][lr][rb + e] = G[e];
      }
      const unsigned short* hp2 = hs + (size_t)(t + 1) * (B_ * H_) +
                                  (size_t)lr * H_ + w * 128 + lk8;
      asm volatile(
          "global_load_dwordx4 %0, %4, off sc0 sc1\n\t"
          "global_load_dwordx4 %1, %4, off offset:64 sc0 sc1\n\t"
          "global_load_dwordx4 %2, %4, off offset:128 sc0 sc1\n\t"
          "global_load_dwordx4 %3, %4, off offset:192 sc0 sc1"
          : "=&v"(u0), "=&v"(u1), "=&v"(u2), "=&v"(u3)
          : "v"(hp2)
          : "memory");
      sv = 1;
    }
  }
}

// ---------------------------------------------------------------- launch
extern "C" void kernel_launch(void* const* d_in, const int* in_sizes, int n_in,
                              void* d_out, int out_size, void* d_ws, size_t ws_size,
                              hipStream_t stream) {
  (void)in_sizes; (void)n_in; (void)out_size; (void)ws_size;
  const float* x    = (const float*)d_in[0];
  const float* w3   = (const float*)d_in[1];
  const float* b3   = (const float*)d_in[2];
  const float* w5   = (const float*)d_in[3];
  const float* b5   = (const float*)d_in[4];
  const float* w7   = (const float*)d_in[5];
  const float* b7   = (const float*)d_in[6];
  const float* wih  = (const float*)d_in[7];
  const float* whh  = (const float*)d_in[8];
  const float* bih  = (const float*)d_in[9];
  const float* bhh  = (const float*)d_in[10];
  // d_in[11..14]: attn_* — dead code (softmax over length-1 axis == 1)
  const float* fiw1 = (const float*)d_in[15];
  const float* fib1 = (const float*)d_in[16];
  const float* fiw2 = (const float*)d_in[17];
  const float* fib2 = (const float*)d_in[18];
  const float* lat  = (const float*)d_in[19];

  char* ws = (char*)d_ws;
  size_t off = 0;
  auto alloc = [&](size_t bytes) -> void* {
    void* p = ws + off;
    off += (bytes + 255) & ~(size_t)255;
    return p;
  };
  unsigned short* whh_bf  = (unsigned short*)alloc((size_t)G3_ * H_ * 2);
  unsigned short* wih_bf  = (unsigned short*)alloc((size_t)G3_ * KIN_ * 2);
  unsigned short* latT_bf = (unsigned short*)alloc((size_t)H_ * H_ * 2);
  unsigned short* fiw1_bf = (unsigned short*)alloc((size_t)H_ * H_ * 2);
  unsigned short* fiw2_bf = (unsigned short*)alloc((size_t)H_ * H_ * 2);
  unsigned short* feat_bf = (unsigned short*)alloc((size_t)B_ * T_ * KIN_ * 2);
  unsigned short* hsbuf   = (unsigned short*)alloc((size_t)(T_ + 1) * B_ * H_ * 2);
  unsigned short* inhib   = (unsigned short*)alloc((size_t)B_ * T_ * H_ * 2);
  unsigned short* y1      = (unsigned short*)alloc((size_t)B_ * T_ * H_ * 2);

  prep_conv_kernel<<<CONVB_ + 2048, 256, 0, stream>>>(
      x, w3, b3, w5, b5, w7, b7, feat_bf,
      whh, whh_bf, wih, wih_bf, fiw1, fiw1_bf, fiw2, fiw2_bf,
      lat, latT_bf, hsbuf, (float*)d_out + (size_t)B_ * T_ * H_);

  gru_scan_kernel<<<64, 512, 0, stream>>>(whh_bf, wih_bf, feat_bf, bhh, bih, hsbuf);

  const unsigned short* hs1 = hsbuf + (size_t)B_ * H_;   // slices 1..T
  {
    dim3 grid(H_ / 128, (B_ * T_) / 128);
    gemm_kernel<1><<<grid, 256, 0, stream>>>(hs1, latT_bf, B_ * T_, H_, H_,
                                             H_, H_, nullptr, nullptr, inhib);
    gemm_kernel<2><<<grid, 256, 0, stream>>>(inhib, fiw1_bf, B_ * T_, H_, H_,
                                             H_, H_, fib1, nullptr, y1);
    gemm_kernel<3><<<grid, 256, 0, stream>>>(y1, fiw2_bf, B_ * T_, H_, H_,
                                             H_, H_, fib2, (float*)d_out, nullptr);
  }
}

// Round 12
// 906.984 us; speedup vs baseline: 1.2161x; 1.2161x over previous
//
#include <hip/hip_runtime.h>
#include <stdint.h>
#include <stddef.h>

#define B_   16
#define T_   256
#define L_   1024
#define H_   1024
#define G3_  3072
#define KIN_ 96
#define CONVB_ 4096

// NaN bf16 pattern: can never be produced by the GRU (|h| <= 1, finite arithmetic)
#define SENT_     0x7FC1
#define SENT_X2_  0x7FC17FC1u

typedef __attribute__((ext_vector_type(8))) __bf16 bf16x8;
typedef __attribute__((ext_vector_type(4))) float  f32x4;
typedef __attribute__((ext_vector_type(4))) int    i32x4;

static __device__ __forceinline__ unsigned short f2bf(float x) {
  unsigned int u = __builtin_bit_cast(unsigned int, x);
  u += 0x7FFFu + ((u >> 16) & 1u);           // RNE
  return (unsigned short)(u >> 16);
}
static __device__ __forceinline__ float bf2f(unsigned short s) {
  unsigned int u = ((unsigned int)s) << 16;
  return __builtin_bit_cast(float, u);
}
// nonzero iff either 16-bit half of d equals the sentinel (exact SWAR detector)
static __device__ __forceinline__ unsigned sentmask(unsigned d) {
  const unsigned x = d ^ SENT_X2_;
  return (x - 0x00010001u) & ~x & 0x80008000u;
}

// ---------------------------------------------------------------- prep+conv
// One dispatch: blocks [0,4096) run conv+pool; remaining blocks grid-stride the
// prep work (bf16 converts, lateral transpose, hs sentinel fill, h0 zero,
// attention-ones). Plain stores; end-of-kernel L2 writeback publishes.
__global__ __launch_bounds__(256) void prep_conv_kernel(
    const float* __restrict__ x,
    const float* __restrict__ w3, const float* __restrict__ b3,
    const float* __restrict__ w5, const float* __restrict__ b5,
    const float* __restrict__ w7, const float* __restrict__ b7,
    unsigned short* __restrict__ feat,
    const float* __restrict__ whh,  unsigned short* __restrict__ whh_bf,
    const float* __restrict__ wih,  unsigned short* __restrict__ wih_bf,
    const float* __restrict__ fiw1, unsigned short* __restrict__ fiw1_bf,
    const float* __restrict__ fiw2, unsigned short* __restrict__ fiw2_bf,
    const float* __restrict__ lat,  unsigned short* __restrict__ latT_bf,
    unsigned short* __restrict__ hsbuf, float* __restrict__ attn_out) {
  __shared__ float xpad[L_ + 8];
  __shared__ float wlds[96][8];
  __shared__ float blds[96];
  __shared__ float wmax[4][96];
  const int tid = threadIdx.x;

  if (blockIdx.x >= CONVB_) {
    const int N0 = G3_ * H_;
    const int N1 = N0 + G3_ * KIN_;
    const int N2 = N1 + H_ * H_;
    const int N3 = N2 + H_ * H_;
    const int N4 = N3 + H_ * H_;             // lat transpose
    const int N5 = N4 + T_ * B_ * H_ / 2;    // hs sentinel (dword units)
    const int N6 = N5 + B_ * H_ / 2;         // hs h0 zero
    const int N7 = N6 + B_ * T_;             // attention ones
    int i = (blockIdx.x - CONVB_) * 256 + tid;
    const int stride = (gridDim.x - CONVB_) * 256;
    unsigned int* hs32 = (unsigned int*)hsbuf;
    for (; i < N7; i += stride) {
      if (i < N0)      whh_bf[i] = f2bf(whh[i]);
      else if (i < N1) { const int j = i - N0; wih_bf[j]  = f2bf(wih[j]); }
      else if (i < N2) { const int j = i - N1; fiw1_bf[j] = f2bf(fiw1[j]); }
      else if (i < N3) { const int j = i - N2; fiw2_bf[j] = f2bf(fiw2[j]); }
      else if (i < N4) { const int j = i - N3; const int r = j >> 10, c = j & 1023;
                         latT_bf[(size_t)c * H_ + r] = f2bf(lat[j]); }
      else if (i < N5) { hs32[B_ * H_ / 2 + (i - N4)] = SENT_X2_; }
      else if (i < N6) { hs32[i - N5] = 0u; }
      else             { attn_out[i - N6] = 1.0f; }
    }
    return;
  }

  const int rid = blockIdx.x;          // b*T + t
  const int b = rid >> 8;
  const int t = rid & 255;
  const float* xr = x + (size_t)rid * L_;
  for (int off = tid; off < L_; off += 256) xpad[off + 3] = xr[off];
  if (tid < 3) xpad[tid] = 0.f;
  if (tid >= 3 && tid < 8) xpad[L_ + tid] = 0.f;
  if (tid < 96) {
    const int f = tid;
    float wv[8];
#pragma unroll
    for (int k = 0; k < 8; ++k) wv[k] = 0.f;
    float bv;
    if (f < 32)      { for (int k = 0; k < 3; ++k) wv[k + 2] = w3[f * 3 + k]; bv = b3[f]; }
    else if (f < 64) { int ff = f - 32; for (int k = 0; k < 5; ++k) wv[k + 1] = w5[ff * 5 + k]; bv = b5[ff]; }
    else             { int ff = f - 64; for (int k = 0; k < 7; ++k) wv[k] = w7[ff * 7 + k]; bv = b7[ff]; }
#pragma unroll
    for (int k = 0; k < 8; ++k) wlds[f][k] = wv[k];
    blds[f] = bv;
  }
  __syncthreads();
  const int w = tid >> 6, lane = tid & 63;
  const int p0 = w * 256 + lane * 4;
  float xv[10];
#pragma unroll
  for (int i = 0; i < 10; ++i) xv[i] = xpad[p0 + i];
  for (int f = 0; f < 96; ++f) {
    float a0 = 0.f, a1 = 0.f, a2 = 0.f, a3 = 0.f;
#pragma unroll
    for (int k = 0; k < 7; ++k) {
      const float wk = wlds[f][k];
      a0 = fmaf(wk, xv[k],     a0);
      a1 = fmaf(wk, xv[k + 1], a1);
      a2 = fmaf(wk, xv[k + 2], a2);
      a3 = fmaf(wk, xv[k + 3], a3);
    }
    float m = fmaxf(fmaxf(a0, a1), fmaxf(a2, a3));
#pragma unroll
    for (int d = 1; d < 64; d <<= 1) m = fmaxf(m, __shfl_xor(m, d, 64));
    if (lane == 0) wmax[w][f] = m;
  }
  __syncthreads();
  if (tid < 96) {
    float m = fmaxf(fmaxf(wmax[0][tid], wmax[1][tid]),
                    fmaxf(wmax[2][tid], wmax[3][tid]));
    m += blds[tid];
    m = m > 0.f ? m : 0.f;
    feat[(size_t)(t * B_ + b) * KIN_ + tid] = f2bf(m);   // row = t*B + b
  }
}

// ---------------------------------------------------------------- GEMM
// C[M,N] = A[M,K] * B[N,K]^T  (both bf16, row-major). 128x128 tile, BK=32,
// 4 waves, double-buffered LDS, padded stride 40.
// EP: 0 = +bias -> f32 (gates); 1 = inhib = bf2f(A) - relu(acc) -> bf16;
//     2 = relu(acc+bias) -> bf16; 3 = acc+bias -> d_out[(b*T+t)*H + col].
template <int EP>
__global__ __launch_bounds__(256) void gemm_kernel(
    const unsigned short* __restrict__ A,
    const unsigned short* __restrict__ Bm,
    int M, int N, int K, int lda, int ldb,
    const float* __restrict__ bias,
    float* __restrict__ outF,
    unsigned short* __restrict__ outB) {
  __shared__ __align__(16) unsigned short As[2][128 * 40];
  __shared__ __align__(16) unsigned short Bs[2][128 * 40];
  const int tid = threadIdx.x;
  const int n0 = blockIdx.x * 128;
  const int m0 = blockIdx.y * 128;
  const int w = tid >> 6;
  const int l = tid & 63;
  const int lr = l & 15;
  const int lk = (l >> 4) * 8;
  const int srow = tid >> 2;
  const int skc = (tid & 3) * 8;

  f32x4 acc[2][8];
#pragma unroll
  for (int i = 0; i < 2; ++i)
#pragma unroll
    for (int j = 0; j < 8; ++j) acc[i][j] = (f32x4){0.f, 0.f, 0.f, 0.f};

  const int NK = K >> 5;
  const unsigned short* Aptr  = A  + (size_t)(m0 + srow)      * lda + skc;
  const unsigned short* Aptr2 = A  + (size_t)(m0 + 64 + srow) * lda + skc;
  const unsigned short* Bptr  = Bm + (size_t)(n0 + srow)      * ldb + skc;
  const unsigned short* Bptr2 = Bm + (size_t)(n0 + 64 + srow) * ldb + skc;

  i32x4 ar0 = *(const i32x4*)(Aptr);
  i32x4 ar1 = *(const i32x4*)(Aptr2);
  i32x4 br0 = *(const i32x4*)(Bptr);
  i32x4 br1 = *(const i32x4*)(Bptr2);
  *(i32x4*)&As[0][srow * 40 + skc]        = ar0;
  *(i32x4*)&As[0][(64 + srow) * 40 + skc] = ar1;
  *(i32x4*)&Bs[0][srow * 40 + skc]        = br0;
  *(i32x4*)&Bs[0][(64 + srow) * 40 + skc] = br1;
  __syncthreads();

  for (int kk = 0; kk < NK; ++kk) {
    const int cur = kk & 1;
    if (kk + 1 < NK) {
      const int ko = (kk + 1) << 5;
      ar0 = *(const i32x4*)(Aptr  + ko);
      ar1 = *(const i32x4*)(Aptr2 + ko);
      br0 = *(const i32x4*)(Bptr  + ko);
      br1 = *(const i32x4*)(Bptr2 + ko);
    }
    const bf16x8 a0 = *(const bf16x8*)&As[cur][(w * 32 + lr) * 40 + lk];
    const bf16x8 a1 = *(const bf16x8*)&As[cur][(w * 32 + 16 + lr) * 40 + lk];
#pragma unroll
    for (int nt = 0; nt < 8; ++nt) {
      const bf16x8 bb = *(const bf16x8*)&Bs[cur][(nt * 16 + lr) * 40 + lk];
      acc[0][nt] = __builtin_amdgcn_mfma_f32_16x16x32_bf16(a0, bb, acc[0][nt], 0, 0, 0);
      acc[1][nt] = __builtin_amdgcn_mfma_f32_16x16x32_bf16(a1, bb, acc[1][nt], 0, 0, 0);
    }
    __syncthreads();
    if (kk + 1 < NK) {
      const int nxt = cur ^ 1;
      *(i32x4*)&As[nxt][srow * 40 + skc]        = ar0;
      *(i32x4*)&As[nxt][(64 + srow) * 40 + skc] = ar1;
      *(i32x4*)&Bs[nxt][srow * 40 + skc]        = br0;
      *(i32x4*)&Bs[nxt][(64 + srow) * 40 + skc] = br1;
    }
    __syncthreads();
  }

#pragma unroll
  for (int mt = 0; mt < 2; ++mt) {
#pragma unroll
    for (int nt = 0; nt < 8; ++nt) {
      const f32x4 v = acc[mt][nt];
      const int gcol = n0 + nt * 16 + lr;
#pragma unroll
      for (int e = 0; e < 4; ++e) {
        const int grow = m0 + w * 32 + mt * 16 + (l >> 4) * 4 + e;
        const float val = v[e];
        if (EP == 0) {
          outF[(size_t)grow * N + gcol] = val + bias[gcol];
        } else if (EP == 1) {
          const float hsv = bf2f(A[(size_t)grow * lda + gcol]);
          outB[(size_t)grow * N + gcol] = f2bf(hsv - fmaxf(val, 0.f));
        } else if (EP == 2) {
          outB[(size_t)grow * N + gcol] = f2bf(fmaxf(val + bias[gcol], 0.f));
        } else {
          const int tt = grow >> 4;   // row = t*B + b
          const int bb2 = grow & 15;
          outF[((size_t)bb2 * T_ + tt) * H_ + gcol] = val + bias[gcol];
        }
      }
    }
  }
}

// ---------------------------------------------------------------- GRU scan
// Round-9 protocol (sentinel data-signal, sc0 sc1, shuffle-packed 16B publish)
// with halved fan-in: 32 WGs x 512 thr, 32 cols/WG. Each consumer wave's poll
// depends on only 4 producer WGs (vs 8). 24 pinned weight quads (96 VGPR)
// under __launch_bounds__(512,1) (256-VGPR budget; round 6's spill was the
// (512,2)=128 cap). Single-buffered LDS partials, 2 barriers/step.
// MFMA C/D mapping (m89): lane l reg e -> D[row=(l>>4)*4+e][col=l&15] with
// row = A-index (weight row j within ct-tile), col = B-index (batch).
// => store ghp[w][m][batch=lr][col32 = ct*16 + rb + e]  (round-11 bug: swapped)
__global__ __launch_bounds__(512, 1) void gru_scan_kernel(
    const unsigned short* __restrict__ Whh,   // [3072][1024] bf16
    const float* __restrict__ gates,          // [T*B][3072] (= x-gates + b_ih)
    const float* __restrict__ bhh,            // [3072]
    unsigned short* __restrict__ hs) {        // [T+1][B][H]; slice0 = 0
  const int g = blockIdx.x;                   // worker id 0..31
  const int tid = threadIdx.x;

  __shared__ float ghp[8][3][16][36];         // [wave][gate][batch][col] 55.3 KB
  const int w = tid >> 6;                     // wave: K-slice [128w, 128w+128)
  const int l = tid & 63;
  const int lr = l & 15;
  const int lk8 = (l >> 4) * 8;
  const int j0 = g * 32;                      // this WG's 32 H-columns

  // ---- one-time: 24 W_hh quads (3 gates x 2 col-tiles x 4 K-frags) into
  // named registers via asm outputs (96 VGPR, no spill at (512,1)).
  const unsigned short* a00 = Whh + (size_t)(0 * H_ + j0 +      lr) * H_ + w * 128 + lk8;
  const unsigned short* a01 = Whh + (size_t)(0 * H_ + j0 + 16 + lr) * H_ + w * 128 + lk8;
  const unsigned short* a10 = Whh + (size_t)(1 * H_ + j0 +      lr) * H_ + w * 128 + lk8;
  const unsigned short* a11 = Whh + (size_t)(1 * H_ + j0 + 16 + lr) * H_ + w * 128 + lk8;
  const unsigned short* a20 = Whh + (size_t)(2 * H_ + j0 +      lr) * H_ + w * 128 + lk8;
  const unsigned short* a21 = Whh + (size_t)(2 * H_ + j0 + 16 + lr) * H_ + w * 128 + lk8;
  i32x4 q0, q1, q2, q3, q4, q5, q6, q7, q8, q9, q10, q11,
        q12, q13, q14, q15, q16, q17, q18, q19, q20, q21, q22, q23;
  asm volatile(
      "global_load_dwordx4 %0,  %24, off\n\t"
      "global_load_dwordx4 %1,  %24, off offset:64\n\t"
      "global_load_dwordx4 %2,  %24, off offset:128\n\t"
      "global_load_dwordx4 %3,  %24, off offset:192\n\t"
      "global_load_dwordx4 %4,  %25, off\n\t"
      "global_load_dwordx4 %5,  %25, off offset:64\n\t"
      "global_load_dwordx4 %6,  %25, off offset:128\n\t"
      "global_load_dwordx4 %7,  %25, off offset:192\n\t"
      "global_load_dwordx4 %8,  %26, off\n\t"
      "global_load_dwordx4 %9,  %26, off offset:64\n\t"
      "global_load_dwordx4 %10, %26, off offset:128\n\t"
      "global_load_dwordx4 %11, %26, off offset:192\n\t"
      "global_load_dwordx4 %12, %27, off\n\t"
      "global_load_dwordx4 %13, %27, off offset:64\n\t"
      "global_load_dwordx4 %14, %27, off offset:128\n\t"
      "global_load_dwordx4 %15, %27, off offset:192\n\t"
      "global_load_dwordx4 %16, %28, off\n\t"
      "global_load_dwordx4 %17, %28, off offset:64\n\t"
      "global_load_dwordx4 %18, %28, off offset:128\n\t"
      "global_load_dwordx4 %19, %28, off offset:192\n\t"
      "global_load_dwordx4 %20, %29, off\n\t"
      "global_load_dwordx4 %21, %29, off offset:64\n\t"
      "global_load_dwordx4 %22, %29, off offset:128\n\t"
      "global_load_dwordx4 %23, %29, off offset:192\n\t"
      "s_waitcnt vmcnt(0)"
      : "=&v"(q0), "=&v"(q1), "=&v"(q2), "=&v"(q3),
        "=&v"(q4), "=&v"(q5), "=&v"(q6), "=&v"(q7),
        "=&v"(q8), "=&v"(q9), "=&v"(q10), "=&v"(q11),
        "=&v"(q12), "=&v"(q13), "=&v"(q14), "=&v"(q15),
        "=&v"(q16), "=&v"(q17), "=&v"(q18), "=&v"(q19),
        "=&v"(q20), "=&v"(q21), "=&v"(q22), "=&v"(q23)
      : "v"(a00), "v"(a01), "v"(a10), "v"(a11), "v"(a20), "v"(a21));
  bf16x8 wf[24];
  wf[0]  = __builtin_bit_cast(bf16x8, q0);  wf[1]  = __builtin_bit_cast(bf16x8, q1);
  wf[2]  = __builtin_bit_cast(bf16x8, q2);  wf[3]  = __builtin_bit_cast(bf16x8, q3);
  wf[4]  = __builtin_bit_cast(bf16x8, q4);  wf[5]  = __builtin_bit_cast(bf16x8, q5);
  wf[6]  = __builtin_bit_cast(bf16x8, q6);  wf[7]  = __builtin_bit_cast(bf16x8, q7);
  wf[8]  = __builtin_bit_cast(bf16x8, q8);  wf[9]  = __builtin_bit_cast(bf16x8, q9);
  wf[10] = __builtin_bit_cast(bf16x8, q10); wf[11] = __builtin_bit_cast(bf16x8, q11);
  wf[12] = __builtin_bit_cast(bf16x8, q12); wf[13] = __builtin_bit_cast(bf16x8, q13);
  wf[14] = __builtin_bit_cast(bf16x8, q14); wf[15] = __builtin_bit_cast(bf16x8, q15);
  wf[16] = __builtin_bit_cast(bf16x8, q16); wf[17] = __builtin_bit_cast(bf16x8, q17);
  wf[18] = __builtin_bit_cast(bf16x8, q18); wf[19] = __builtin_bit_cast(bf16x8, q19);
  wf[20] = __builtin_bit_cast(bf16x8, q20); wf[21] = __builtin_bit_cast(bf16x8, q21);
  wf[22] = __builtin_bit_cast(bf16x8, q22); wf[23] = __builtin_bit_cast(bf16x8, q23);

  const int jb = tid & 31;   // col within WG's 32
  const int bb = tid >> 5;   // batch (all 512 threads: 16b x 32j)
  const float bhr = bhh[j0 + jb];
  const float bhz = bhh[H_ + j0 + jb];
  const float bhn = bhh[2 * H_ + j0 + jb];
  float hprev = 0.f;

  for (int t = 0; t < T_; ++t) {
    // x-gates for this step (independent of h; issued before the poll)
    const size_t grow = ((size_t)t * B_ + bb) * G3_;
    const float gxr = gates[grow + j0 + jb];
    const float gxz = gates[grow + H_ + j0 + jb];
    const float gxn = gates[grow + 2 * H_ + j0 + jb];

    // Poll-load h_t fragments through the coherence point until sentinel-free.
    // Each 16B unit stored atomically -> check dwords 0 and 3.
    const unsigned short* hp = hs + (size_t)t * (B_ * H_) +
                               (size_t)lr * H_ + w * 128 + lk8;
    i32x4 u0, u1, u2, u3;
    while (true) {
      asm volatile(
          "global_load_dwordx4 %0, %4, off sc0 sc1\n\t"
          "global_load_dwordx4 %1, %4, off offset:64 sc0 sc1\n\t"
          "global_load_dwordx4 %2, %4, off offset:128 sc0 sc1\n\t"
          "global_load_dwordx4 %3, %4, off offset:192 sc0 sc1\n\t"
          "s_waitcnt vmcnt(0)"
          : "=&v"(u0), "=&v"(u1), "=&v"(u2), "=&v"(u3)
          : "v"(hp)
          : "memory");
      const unsigned bad = sentmask(u0[0]) | sentmask(u0[3]) |
                           sentmask(u1[0]) | sentmask(u1[3]) |
                           sentmask(u2[0]) | sentmask(u2[3]) |
                           sentmask(u3[0]) | sentmask(u3[3]);
      if (__ballot(bad == 0) == ~0ull) break;
    }
    const bf16x8 hf0 = __builtin_bit_cast(bf16x8, u0);
    const bf16x8 hf1 = __builtin_bit_cast(bf16x8, u1);
    const bf16x8 hf2 = __builtin_bit_cast(bf16x8, u2);
    const bf16x8 hf3 = __builtin_bit_cast(bf16x8, u3);

    f32x4 C[3][2];
#pragma unroll
    for (int m = 0; m < 3; ++m)
#pragma unroll
      for (int ct = 0; ct < 2; ++ct) C[m][ct] = (f32x4){0.f, 0.f, 0.f, 0.f};
#pragma unroll
    for (int m = 0; m < 3; ++m)
#pragma unroll
      for (int ct = 0; ct < 2; ++ct) {
        C[m][ct] = __builtin_amdgcn_mfma_f32_16x16x32_bf16(wf[(m * 2 + ct) * 4 + 0], hf0, C[m][ct], 0, 0, 0);
        C[m][ct] = __builtin_amdgcn_mfma_f32_16x16x32_bf16(wf[(m * 2 + ct) * 4 + 1], hf1, C[m][ct], 0, 0, 0);
        C[m][ct] = __builtin_amdgcn_mfma_f32_16x16x32_bf16(wf[(m * 2 + ct) * 4 + 2], hf2, C[m][ct], 0, 0, 0);
        C[m][ct] = __builtin_amdgcn_mfma_f32_16x16x32_bf16(wf[(m * 2 + ct) * 4 + 3], hf3, C[m][ct], 0, 0, 0);
      }

    const int rb = (l >> 4) * 4;
    // C[m][ct][e] = D[j = ct*16 + rb+e][batch = lr]  ->  ghp[w][m][lr][ct*16+rb+e]
#pragma unroll
    for (int m = 0; m < 3; ++m)
#pragma unroll
      for (int ct = 0; ct < 2; ++ct)
#pragma unroll
        for (int e = 0; e < 4; ++e)
          ghp[w][m][lr][ct * 16 + rb + e] = C[m][ct][e];
    __syncthreads();

    // all 512 threads: one (batch, col) output each
    float hr = bhr, hz = bhz, hn = bhn;
#pragma unroll
    for (int w2 = 0; w2 < 8; ++w2) {
      hr += ghp[w2][0][bb][jb];
      hz += ghp[w2][1][bb][jb];
      hn += ghp[w2][2][bb][jb];
    }
    const float r = 1.f / (1.f + __expf(-(gxr + hr)));
    const float z = 1.f / (1.f + __expf(-(gxz + hz)));
    const float xn = gxn + r * hn;
    const float n = 2.f / (1.f + __expf(-2.f * xn)) - 1.f;
    const float hnew = (1.f - z) * n + z * hprev;   // carry stays fp32
    hprev = hnew;

    // shuffle-pack 8 consecutive cols into one lane; 16B coalesced publish
    const unsigned hv = (unsigned)f2bf(hnew);
    const int base = l & ~7;
    const unsigned s0 = __shfl(hv, base + 0, 64);
    const unsigned s1 = __shfl(hv, base + 1, 64);
    const unsigned s2 = __shfl(hv, base + 2, 64);
    const unsigned s3 = __shfl(hv, base + 3, 64);
    const unsigned s4 = __shfl(hv, base + 4, 64);
    const unsigned s5 = __shfl(hv, base + 5, 64);
    const unsigned s6 = __shfl(hv, base + 6, 64);
    const unsigned s7 = __shfl(hv, base + 7, 64);
    i32x4 pk;
    pk[0] = (int)(s0 | (s1 << 16));
    pk[1] = (int)(s2 | (s3 << 16));
    pk[2] = (int)(s4 | (s5 << 16));
    pk[3] = (int)(s6 | (s7 << 16));
    if ((l & 7) == 0) {
      unsigned short* sp = hs + ((size_t)(t + 1) * B_ + bb) * H_ + j0 + jb;
      asm volatile("global_store_dwordx4 %0, %1, off sc0 sc1"
                   :: "v"(sp), "v"(pk) : "memory");
    }
    __syncthreads();   // protect ghp overwrite next step (single buffer)
  }
}

// ---------------------------------------------------------------- launch
extern "C" void kernel_launch(void* const* d_in, const int* in_sizes, int n_in,
                              void* d_out, int out_size, void* d_ws, size_t ws_size,
                              hipStream_t stream) {
  (void)in_sizes; (void)n_in; (void)out_size; (void)ws_size;
  const float* x    = (const float*)d_in[0];
  const float* w3   = (const float*)d_in[1];
  const float* b3   = (const float*)d_in[2];
  const float* w5   = (const float*)d_in[3];
  const float* b5   = (const float*)d_in[4];
  const float* w7   = (const float*)d_in[5];
  const float* b7   = (const float*)d_in[6];
  const float* wih  = (const float*)d_in[7];
  const float* whh  = (const float*)d_in[8];
  const float* bih  = (const float*)d_in[9];
  const float* bhh  = (const float*)d_in[10];
  // d_in[11..14]: attn_* — dead code (softmax over length-1 axis == 1)
  const float* fiw1 = (const float*)d_in[15];
  const float* fib1 = (const float*)d_in[16];
  const float* fiw2 = (const float*)d_in[17];
  const float* fib2 = (const float*)d_in[18];
  const float* lat  = (const float*)d_in[19];

  char* ws = (char*)d_ws;
  size_t off = 0;
  auto alloc = [&](size_t bytes) -> void* {
    void* p = ws + off;
    off += (bytes + 255) & ~(size_t)255;
    return p;
  };
  unsigned short* whh_bf  = (unsigned short*)alloc((size_t)G3_ * H_ * 2);
  unsigned short* wih_bf  = (unsigned short*)alloc((size_t)G3_ * KIN_ * 2);
  unsigned short* latT_bf = (unsigned short*)alloc((size_t)H_ * H_ * 2);
  unsigned short* fiw1_bf = (unsigned short*)alloc((size_t)H_ * H_ * 2);
  unsigned short* fiw2_bf = (unsigned short*)alloc((size_t)H_ * H_ * 2);
  unsigned short* feat_bf = (unsigned short*)alloc((size_t)B_ * T_ * KIN_ * 2);
  float*          gates   = (float*)alloc((size_t)B_ * T_ * G3_ * 4);
  unsigned short* hsbuf   = (unsigned short*)alloc((size_t)(T_ + 1) * B_ * H_ * 2);
  unsigned short* inhib   = (unsigned short*)alloc((size_t)B_ * T_ * H_ * 2);
  unsigned short* y1      = (unsigned short*)alloc((size_t)B_ * T_ * H_ * 2);

  prep_conv_kernel<<<CONVB_ + 2048, 256, 0, stream>>>(
      x, w3, b3, w5, b5, w7, b7, feat_bf,
      whh, whh_bf, wih, wih_bf, fiw1, fiw1_bf, fiw2, fiw2_bf,
      lat, latT_bf, hsbuf, (float*)d_out + (size_t)B_ * T_ * H_);

  {
    dim3 grid(G3_ / 128, (B_ * T_) / 128);
    gemm_kernel<0><<<grid, 256, 0, stream>>>(feat_bf, wih_bf, B_ * T_, G3_, KIN_,
                                             KIN_, KIN_, bih, gates, nullptr);
  }

  gru_scan_kernel<<<32, 512, 0, stream>>>(whh_bf, gates, bhh, hsbuf);

  const unsigned short* hs1 = hsbuf + (size_t)B_ * H_;   // slices 1..T
  {
    dim3 grid(H_ / 128, (B_ * T_) / 128);
    gemm_kernel<1><<<grid, 256, 0, stream>>>(hs1, latT_bf, B_ * T_, H_, H_,
                                             H_, H_, nullptr, nullptr, inhib);
    gemm_kernel<2><<<grid, 256, 0, stream>>>(inhib, fiw1_bf, B_ * T_, H_, H_,
                                             H_, H_, fib1, nullptr, y1);
    gemm_kernel<3><<<grid, 256, 0, stream>>>(y1, fiw2_bf, B_ * T_, H_, H_,
                                             H_, H_, fib2, (float*)d_out, nullptr);
  }
}